// Round 1
// baseline (20238.887 us; speedup 1.0000x reference)
//
#include <hip/hip_runtime.h>

// RNN scan: h_{t} = tanh(h_{t-1} @ W + x_t @ V + b + b2), 512 steps.
// Persistent kernel, 256 wgs x 1024 threads (16 waves), exactly 1 wg/CU.
//   - group g = blockIdx.x>>4 owns batches [4g, 4g+4)
//   - chunk c = blockIdx.x&15 owns output columns [64c, 64c+64)
//   - wave w  owns k-slice [64w, 64w+64) of W (64 VGPRs/lane) and
//     k-slice [16w, 16w+16) of V (16 VGPRs/lane); lane = column.
// h is exchanged through d_out (chunk t of h_seq IS h_t) with agent-scope
// atomics; 16-wg groups sync via a monotonic counter barrier in d_ws.

#define SEQ    512
#define BATCH  64
#define INSZ   256
#define HID    1024
#define BPG    4     // batches per group
#define NWAVE  16
#define OUT_SEQ (SEQ * BATCH * HID)

__device__ __forceinline__ float ld_agent(const float* p) {
    return __hip_atomic_load(p, __ATOMIC_RELAXED, __HIP_MEMORY_SCOPE_AGENT);
}
__device__ __forceinline__ void st_agent(float* p, float v) {
    __hip_atomic_store(p, v, __ATOMIC_RELAXED, __HIP_MEMORY_SCOPE_AGENT);
}

__global__ __launch_bounds__(1024, 4) void rnn_scan_kernel(
    const float* __restrict__ x,   // (SEQ, BATCH, INSZ)
    const float* __restrict__ V,   // (INSZ, HID)
    const float* __restrict__ W,   // (HID, HID)
    const float* __restrict__ b1,  // (HID,)
    const float* __restrict__ b2,  // (HID,)
    float* __restrict__ out,       // h_seq (SEQ*BATCH*HID) then h_last (BATCH*HID)
    unsigned int* __restrict__ cnt)
{
    const int tid  = threadIdx.x;
    const int w    = tid >> 6;      // wave 0..15
    const int lane = tid & 63;
    const int g    = blockIdx.x >> 4;   // batch group 0..15
    const int c    = blockIdx.x & 15;   // column chunk 0..15
    const int jcol = c * 64 + lane;     // this lane's output column

    __shared__ __align__(16) float h_lds[BPG][HID];        // 16 KB
    __shared__ __align__(16) float pacc[NWAVE][64][BPG];   // 16 KB

    // ---- persistent register-resident W and V fragments (one-time load) ----
    float Wreg[64];
#pragma unroll
    for (int i = 0; i < 64; ++i)
        Wreg[i] = W[(size_t)(w * 64 + i) * HID + jcol];
    float Vreg[16];
#pragma unroll
    for (int i = 0; i < 16; ++i)
        Vreg[i] = V[(size_t)(w * 16 + i) * HID + jcol];

    const float bias = b1[jcol] + b2[jcol];
    unsigned int* mycnt = cnt + g * 16;   // 64B-padded per-group counter

    for (int t = 0; t < SEQ; ++t) {
        // ---- stage previous h (coherent: written by other CUs) ----
        if (t > 0) {
            const float* hprev = out + (size_t)(t - 1) * (BATCH * HID)
                                     + (size_t)g * BPG * HID;
#pragma unroll
            for (int i = 0; i < BPG; ++i)
                h_lds[i][tid] = ld_agent(hprev + i * HID + tid);
        }
        __syncthreads();

        float acc[BPG] = {0.f, 0.f, 0.f, 0.f};

        // ---- x_t @ V contribution (k-slice 16w..16w+16) ----
        {
            const float* xt = x + (size_t)t * (BATCH * INSZ)
                                + (size_t)g * BPG * INSZ + w * 16;
#pragma unroll
            for (int b = 0; b < BPG; ++b) {
#pragma unroll
                for (int q = 0; q < 4; ++q) {
                    const float4 xa =
                        *reinterpret_cast<const float4*>(xt + b * INSZ + 4 * q);
                    acc[b] += xa.x * Vreg[4 * q + 0];
                    acc[b] += xa.y * Vreg[4 * q + 1];
                    acc[b] += xa.z * Vreg[4 * q + 2];
                    acc[b] += xa.w * Vreg[4 * q + 3];
                }
            }
        }

        // ---- h_{t-1} @ W contribution (k-slice 64w..64w+64) ----
        if (t > 0) {
#pragma unroll
            for (int q = 0; q < 16; ++q) {
#pragma unroll
                for (int b = 0; b < BPG; ++b) {
                    const float4 hv = *reinterpret_cast<const float4*>(
                        &h_lds[b][w * 64 + 4 * q]);   // uniform addr: broadcast
                    acc[b] += hv.x * Wreg[4 * q + 0];
                    acc[b] += hv.y * Wreg[4 * q + 1];
                    acc[b] += hv.z * Wreg[4 * q + 2];
                    acc[b] += hv.w * Wreg[4 * q + 3];
                }
            }
        }

        // ---- cross-wave K reduction through LDS ----
        *reinterpret_cast<float4*>(&pacc[w][lane][0]) =
            make_float4(acc[0], acc[1], acc[2], acc[3]);
        __syncthreads();

        if (w < BPG) {
            const int b = w;
            float s = 0.f;
#pragma unroll
            for (int ww = 0; ww < NWAVE; ++ww) s += pacc[ww][lane][b];
            const float hval = tanhf(s + bias);
            float* dst = out + (size_t)t * (BATCH * HID)
                             + (size_t)(g * BPG + b) * HID + jcol;
            st_agent(dst, hval);                 // next step's h input
            if (t == SEQ - 1) {
                st_agent(out + (size_t)OUT_SEQ
                             + (size_t)(g * BPG + b) * HID + jcol, hval);
            }
        }
        __syncthreads();   // h stores drained (vmcnt(0) before s_barrier)

        // ---- 16-wg group barrier (monotonic counter, agent scope) ----
        if (t < SEQ - 1) {
            if (tid == 0) {
                __threadfence();
                __hip_atomic_fetch_add(mycnt, 1u, __ATOMIC_ACQ_REL,
                                       __HIP_MEMORY_SCOPE_AGENT);
                const unsigned int target = 16u * (unsigned int)(t + 1);
                while (__hip_atomic_load(mycnt, __ATOMIC_ACQUIRE,
                                         __HIP_MEMORY_SCOPE_AGENT) < target) {
                    __builtin_amdgcn_s_sleep(2);
                }
                __threadfence();
            }
            __syncthreads();
        }
    }
}

extern "C" void kernel_launch(void* const* d_in, const int* in_sizes, int n_in,
                              void* d_out, int out_size, void* d_ws, size_t ws_size,
                              hipStream_t stream) {
    (void)in_sizes; (void)n_in; (void)out_size; (void)ws_size;
    const float* x  = (const float*)d_in[0];
    const float* V  = (const float*)d_in[1];
    const float* W  = (const float*)d_in[2];
    const float* b1 = (const float*)d_in[3];
    const float* b2 = (const float*)d_in[4];
    float* out = (float*)d_out;
    unsigned int* cnt = (unsigned int*)d_ws;

    // zero the per-group barrier counters (ws is poisoned 0xAA every launch)
    hipMemsetAsync(d_ws, 0, 1024, stream);

    hipLaunchKernelGGL(rnn_scan_kernel, dim3(256), dim3(1024), 0, stream,
                       x, V, W, b1, b2, out, cnt);
}